// Round 17
// baseline (344.132 us; speedup 1.0000x reference)
//
#include <hip/hip_runtime.h>
#include <hip/hip_bf16.h>

#define NB 22
#define NFR_B 7499
#define BATCH 32
#define ROWLEN 960000
#define NFTOT (BATCH * NFR_B)   // 239968

typedef float f32x16 __attribute__((ext_vector_type(16)));
typedef short short8 __attribute__((ext_vector_type(8)));

// DFT matrix in MFMA A-fragment order, bf16 bits. 128 KB.
// layout: [pair p(4)][re/im(2)][kstep(16)][lane(64)][j(8)]
// value:  bin = 32p + (lane&31); k = 16*kstep + 8*(lane>>5) + j
//         re: win[k]*cos(pi*bin*k/128), im: win[k]*sin(...)  (sign-free: squared later)
__device__ __align__(16) unsigned short g_awf[65536];

__global__ void gen_a_kernel() {
    const int idx = blockIdx.x * blockDim.x + threadIdx.x;  // 0..65535
    const int j = idx & 7;
    const int lane = (idx >> 3) & 63;
    const int kstep = (idx >> 9) & 15;
    const int ri = (idx >> 13) & 1;
    const int p = idx >> 14;
    const int bin = 32 * p + (lane & 31);
    const int k = 16 * kstep + 8 * (lane >> 5) + j;
    const float PI = 3.14159265358979323846f;
    const float win = sinf(PI * (float)k / 256.0f);
    const float ang = PI * (float)(bin * k) / 128.0f;
    const float val = win * (ri ? sinf(ang) : cosf(ang));
    __hip_bfloat16 b = __float2bfloat16(val);
    g_awf[idx] = *reinterpret_cast<unsigned short*>(&b);
}

// triangular band weight W[c][k] (reference semantics), compile-time foldable
__device__ constexpr int BND[22] = {0,4,8,12,16,20,24,28,32,40,44,48,52,56,64,72,80,88,96,104,112,128};
__device__ constexpr float Wfn(int c, int k) {
    int j = 0;
    for (int t = 1; t < 21; ++t) if (k >= BND[t]) j = t;  // segment [BND[j], BND[j+1])
    const float alpha = (float)(k - BND[j]) / (float)(BND[j + 1] - BND[j]);
    float w = 0.0f;
    if (c == j)     w = 1.0f - alpha;   // falling part of band j
    if (c == j + 1) w = alpha;          // rising part of band j+1
    if (c == 0)  w *= 2.0f;             // edge bands doubled (only j==0 case nonzero)
    if (c == 21) w *= 2.0f;             // only j==20 rising case nonzero
    return w;
}

// permlane32 self-swap: A = lo-half's value, B = hi-half's value (verified R12)
struct fpair { float A, B; };
__device__ __forceinline__ fpair bh32(float v) {
    const unsigned u = __float_as_uint(v);
    const auto p = __builtin_amdgcn_permlane32_swap(u, u, false, false);
    fpair r; r.A = __uint_as_float(p[0]); r.B = __uint_as_float(p[1]); return r;
}

// pack 2 f32 -> 1 u32 of 2 bf16 (truncation) via v_perm
__device__ __forceinline__ unsigned pk(float hi, float lo) {
    return __builtin_amdgcn_perm(__float_as_uint(hi), __float_as_uint(lo), 0x07060302u);
}
__device__ __forceinline__ short8 mk_bfrag(float4 lo, float4 hi) {
    int4 u;
    u.x = (int)pk(lo.y, lo.x);
    u.y = (int)pk(lo.w, lo.z);
    u.z = (int)pk(hi.y, hi.x);
    u.w = (int)pk(hi.w, hi.z);
    return *reinterpret_cast<short8*>(&u);
}

__global__ __launch_bounds__(256, 1)
void feat_mfma(const float* __restrict__ x, float* __restrict__ out) {
    const int lane = threadIdx.x & 63;
    const int wid  = threadIdx.x >> 6;
    const int chunk = blockIdx.x * 4 + wid;       // one 64-frame chunk per wave
    const int F = chunk * 64;
    if (F >= NFTOT) return;

    const int col = lane & 31;                    // frame within 32-col block
    const int h   = lane >> 5;
    const float hf = (float)h;

    // two column blocks of 32 frames
    const int m0c = F + col;
    const int m1c = F + 32 + col;
    const int m0 = (m0c < NFTOT) ? m0c : NFTOT - 1;
    const int m1 = (m1c < NFTOT) ? m1c : NFTOT - 1;
    const int b0 = m0 / NFR_B, t0_ = m0 - b0 * NFR_B;
    const int b1 = m1 / NFR_B, t1_ = m1 - b1 * NFR_B;
    const float* xb0 = x + (size_t)b0 * ROWLEN + (size_t)t0_ * 128 + 8 * h;
    const float* xb1 = x + (size_t)b1 * ROWLEN + (size_t)t1_ * 128 + 8 * h;

    float partial0[NB], partial1[NB];
    #pragma unroll
    for (int c = 0; c < NB; ++c) { partial0[c] = 0.0f; partial1[c] = 0.0f; }

    #pragma unroll
    for (int p = 0; p < 4; ++p) {
        f32x16 accr0 = {}; f32x16 acci0 = {};
        f32x16 accr1 = {}; f32x16 acci1 = {};
        #pragma unroll
        for (int ks = 0; ks < 16; ++ks) {
            const short8 ar = *(const short8*)(g_awf + (((size_t)(p * 2 + 0) * 16 + ks) * 64 + lane) * 8);
            const short8 ai = *(const short8*)(g_awf + (((size_t)(p * 2 + 1) * 16 + ks) * 64 + lane) * 8);
            const float4 lo0 = *(const float4*)(xb0 + 16 * ks);
            const float4 hi0 = *(const float4*)(xb0 + 16 * ks + 4);
            const float4 lo1 = *(const float4*)(xb1 + 16 * ks);
            const float4 hi1 = *(const float4*)(xb1 + 16 * ks + 4);
            const short8 bf0 = mk_bfrag(lo0, hi0);
            const short8 bf1 = mk_bfrag(lo1, hi1);
            accr0 = __builtin_amdgcn_mfma_f32_32x32x16_bf16(ar, bf0, accr0, 0, 0, 0);
            acci0 = __builtin_amdgcn_mfma_f32_32x32x16_bf16(ai, bf0, acci0, 0, 0, 0);
            accr1 = __builtin_amdgcn_mfma_f32_32x32x16_bf16(ar, bf1, accr1, 0, 0, 0);
            acci1 = __builtin_amdgcn_mfma_f32_32x32x16_bf16(ai, bf1, acci1, 0, 0, 0);
        }
        // pw -> band partials (weights compile-time; h-dependence via one fmaf)
        #pragma unroll
        for (int r = 0; r < 16; ++r) {
            const float pw0 = accr0[r] * accr0[r] + acci0[r] * acci0[r];
            const float pw1 = accr1[r] * accr1[r] + acci1[r] * acci1[r];
            const int bin0 = 32 * p + (r & 3) + 8 * (r >> 2);   // bin at h=0; +4 at h=1
            #pragma unroll
            for (int c = 0; c < NB; ++c) {
                const float w0 = Wfn(c, bin0);
                const float w1 = Wfn(c, bin0 + 4);
                if (w0 != 0.0f || w1 != 0.0f) {
                    const float w = fmaf(hf, w1 - w0, w0);
                    partial0[c] = fmaf(w, pw0, partial0[c]);
                    partial1[c] = fmaf(w, pw1, partial1[c]);
                }
            }
        }
    }

    // combine lane-halves (each holds its h's bins) -> full band power; log2
    float lg0[NB], lg1[NB];
    #pragma unroll
    for (int c = 0; c < NB; ++c) {
        const fpair q0 = bh32(partial0[c]);
        lg0[c] = __log2f(q0.A + q0.B);
        const fpair q1 = bh32(partial1[c]);
        lg1[c] = __log2f(q1.A + q1.B);
    }

    // DCT-II via Chebyshev recurrence; h-split over output index
    const float PI = 3.14159265358979323846f;
    const float SC = 0.30102999566398120f * 0.30151134457776363f; // log10(2)*sqrt(2/22)
    const int ocb = h * 11;
    const bool v0 = (m0c < NFTOT), v1 = (m1c < NFTOT);
    float* o0 = out + (size_t)m0c * NB;
    float* o1 = out + (size_t)m1c * NB;
    #pragma unroll
    for (int ol = 0; ol < 11; ++ol) {
        const int oc = ocb + ol;
        const float th = PI * (float)oc / 22.0f;
        const float cth2 = 2.0f * cosf(th);
        float fm = cosf(0.5f * th);     // f(-1) = f(0)
        float fc = fm;
        float a0 = fc * lg0[0], a1 = fc * lg1[0];
        #pragma unroll
        for (int c = 1; c < NB; ++c) {
            const float fn = fmaf(cth2, fc, -fm);
            fm = fc; fc = fn;
            a0 = fmaf(fc, lg0[c], a0);
            a1 = fmaf(fc, lg1[c], a1);
        }
        float sc = SC;
        if (oc == 0) sc *= 0.70710678118654752f;
        if (v0) o0[oc] = a0 * sc;
        if (v1) o1[oc] = a1 * sc;
    }
}

extern "C" void kernel_launch(void* const* d_in, const int* in_sizes, int n_in,
                              void* d_out, int out_size, void* d_ws, size_t ws_size,
                              hipStream_t stream) {
    const float* x = (const float*)d_in[0];
    float* out = (float*)d_out;
    gen_a_kernel<<<256, 256, 0, stream>>>();
    // 3750 chunks of 64 frames, 4 waves per block
    feat_mfma<<<938, 256, 0, stream>>>(x, out);
}

// Round 18
// 229.281 us; speedup vs baseline: 1.5009x; 1.5009x over previous
//
#include <hip/hip_runtime.h>
#include <hip/hip_bf16.h>

#define NB 22
#define NFR_B 7499
#define BATCH 32
#define ROWLEN 960000
#define NFTOT (BATCH * NFR_B)
#define CPR 235                 // chunks per batch row (234 full + 1 ragged)
#define NCHUNK (BATCH * CPR)    // 7520

typedef float f32x16 __attribute__((ext_vector_type(16)));
typedef short short8 __attribute__((ext_vector_type(8)));

__device__ constexpr int BND[22] = {0,4,8,12,16,20,24,28,32,40,44,48,52,56,64,72,80,88,96,104,112,128};
__device__ constexpr float Wfn(int c, int k) {
    int j = 0;
    for (int t = 1; t < 21; ++t) if (k >= BND[t]) j = t;   // segment [BND[j], BND[j+1])
    const float alpha = (float)(k - BND[j]) / (float)(BND[j + 1] - BND[j]);
    float w = 0.0f;
    if (c == j)     w = 1.0f - alpha;     // falling part of band j
    if (c == j + 1) w = alpha;            // rising part of band j+1
    if (c == 0 || c == 21) w *= 2.0f;     // edge bands doubled
    return w;
}

// permlane32 self-swap: A = lo-half value, B = hi-half value (verified R12/R17)
struct fpair { float A, B; };
__device__ __forceinline__ fpair bh32(float v) {
    const unsigned u = __float_as_uint(v);
    const auto p = __builtin_amdgcn_permlane32_swap(u, u, false, false);
    fpair r; r.A = __uint_as_float(p[0]); r.B = __uint_as_float(p[1]); return r;
}

// pack 2 f32 -> u32 of 2 bf16 (truncation; verified R17)
__device__ __forceinline__ unsigned pk(float hi, float lo) {
    return __builtin_amdgcn_perm(__float_as_uint(hi), __float_as_uint(lo), 0x07060302u);
}
__device__ __forceinline__ short8 mk_bfrag(float4 lo, float4 hi) {
    int4 u;
    u.x = (int)pk(lo.y, lo.x);
    u.y = (int)pk(lo.w, lo.z);
    u.z = (int)pk(hi.y, hi.x);
    u.w = (int)pk(hi.w, hi.z);
    return *reinterpret_cast<short8*>(&u);
}

// band-fold with compile-time bin block P (weights fold to constants)
template<int P>
__device__ __forceinline__ void foldP(const f32x16& accr, const f32x16& acci,
                                      float hf, float* partial) {
    #pragma unroll
    for (int r = 0; r < 16; ++r) {
        const float pw = accr[r] * accr[r] + acci[r] * acci[r];
        const int bin0 = 32 * P + (r & 3) + 8 * (r >> 2);   // bin at h=0; +4 at h=1
        #pragma unroll
        for (int c = 0; c < NB; ++c) {
            const float w0 = Wfn(c, bin0);
            const float w1 = Wfn(c, bin0 + 4);
            if (w0 != 0.0f || w1 != 0.0f) {
                partial[c] = fmaf(fmaf(hf, w1 - w0, w0), pw, partial[c]);
            }
        }
    }
}

__global__ __launch_bounds__(256, 1)
void feat_mfma2(const float* __restrict__ x, float* __restrict__ out) {
    const int lane = threadIdx.x & 63;
    const int wid  = threadIdx.x >> 6;      // wave owns bin pair-block p = wid
    const int col  = lane & 31;             // frame column within chunk
    const int h    = lane >> 5;
    const float hf = (float)h;

    __shared__ float xs[33 * 128];          // 16.9 KB, XOR-swizzled rows of 512B
    __shared__ float comb[4 * 32 * NB];     // 11.3 KB band-partial combine

    // ---- A (DFT rows for this wave's 32 bins) resident in 128 VGPRs, bf16 ----
    const int bin = 32 * wid + col;
    short8 ar[16], ai[16];
    #pragma unroll
    for (int ks = 0; ks < 16; ++ks) {
        #pragma unroll
        for (int j = 0; j < 8; ++j) {
            const int k = 16 * ks + 8 * h + j;
            const float win = __sinf(3.14159265358979f * (float)k * (1.0f / 256.0f));
            const int bk = (bin * k) & 255;                       // exact phase mod 2pi
            const float ph = 6.28318530717959f * (float)bk * (1.0f / 256.0f);
            const __hip_bfloat16 vr = __float2bfloat16(win * __cosf(ph));
            const __hip_bfloat16 vi = __float2bfloat16(win * __sinf(ph));
            ar[ks][j] = *reinterpret_cast<const short*>(&vr);
            ai[ks][j] = *reinterpret_cast<const short*>(&vi);
        }
    }

    for (int ch = blockIdx.x; ch < NCHUNK; ch += gridDim.x) {
        const int row = ch / CPR;
        const int loc = ch - row * CPR;
        const int t   = loc * 32;                       // first frame (in row) of chunk
        const float* xrow = x + (size_t)row * ROWLEN;

        __syncthreads();   // previous iteration's readers done before overwrite
        // stage 33 x 128 floats, coalesced, XOR-swizzled; clamp supplies row tail
        for (int i = threadIdx.x; i < 33 * 32; i += 256) {
            const int jj = i >> 5;
            const int of = i & 31;
            int src = (t + jj) * 128;
            if (src > ROWLEN - 128) src = ROWLEN - 128;   // = frame 7498's tail window
            const float4 v = *(const float4*)(xrow + src + of * 4);
            const int dst = (jj * 512 + of * 16) ^ ((jj & 7) << 4);
            *(float4*)((char*)xs + dst) = v;
        }
        __syncthreads();

        // ---- 32 MFMAs: C[bin][frame] over K=256, A in regs, B from LDS ----
        f32x16 accr = {}; f32x16 acci = {};
        #pragma unroll
        for (int ks = 0; ks < 16; ++ks) {
            const int kb = 16 * ks + 8 * h;
            const int jj = col + (kb >> 7);
            const int km = kb & 127;
            const int sw = (jj & 7) << 4;
            const int a1 = (jj * 512 + km * 4) ^ sw;
            const int a2 = (jj * 512 + km * 4 + 16) ^ sw;
            const float4 lo = *(const float4*)((const char*)xs + a1);
            const float4 hi = *(const float4*)((const char*)xs + a2);
            const short8 bf = mk_bfrag(lo, hi);
            accr = __builtin_amdgcn_mfma_f32_32x32x16_bf16(ar[ks], bf, accr, 0, 0, 0);
            acci = __builtin_amdgcn_mfma_f32_32x32x16_bf16(ai[ks], bf, acci, 0, 0, 0);
        }

        // ---- fold pw into band partials (compile-time weights) ----
        float partial[NB];
        #pragma unroll
        for (int c = 0; c < NB; ++c) partial[c] = 0.0f;
        switch (wid) {
            case 0: foldP<0>(accr, acci, hf, partial); break;
            case 1: foldP<1>(accr, acci, hf, partial); break;
            case 2: foldP<2>(accr, acci, hf, partial); break;
            default: foldP<3>(accr, acci, hf, partial); break;
        }
        #pragma unroll
        for (int c = 0; c < NB; ++c) {
            const fpair q = bh32(partial[c]);     // combine h halves
            partial[c] = q.A + q.B;
        }
        if (lane < 32) {
            #pragma unroll
            for (int c = 0; c < NB; ++c)
                comb[(wid * 32 + col) * NB + c] = partial[c];
        }
        __syncthreads();

        // ---- epilogue: sum 4 bin-blocks, log, Chebyshev DCT (verified R17) ----
        const int fr = t + col;
        if (fr < NFR_B) {
            float lg[NB];
            #pragma unroll
            for (int c = 0; c < NB; ++c) {
                const float b = comb[(0 * 32 + col) * NB + c]
                              + comb[(1 * 32 + col) * NB + c]
                              + comb[(2 * 32 + col) * NB + c]
                              + comb[(3 * 32 + col) * NB + c];
                lg[c] = __log2f(b);
            }
            const float PI = 3.14159265358979323846f;
            const float SC = 0.30102999566398120f * 0.30151134457776363f; // log10(2)*sqrt(2/22)
            float* o = out + ((size_t)row * NFR_B + fr) * NB;
            #pragma unroll
            for (int ol = 0; ol < 11; ++ol) {
                const int oc = h * 11 + ol;
                const float th = PI * (float)oc / 22.0f;
                const float cth2 = 2.0f * cosf(th);
                float fm = cosf(0.5f * th);
                float fc = fm;
                float a = fc * lg[0];
                #pragma unroll
                for (int c = 1; c < NB; ++c) {
                    const float fn = fmaf(cth2, fc, -fm);
                    fm = fc; fc = fn;
                    a = fmaf(fc, lg[c], a);
                }
                o[oc] = a * ((oc == 0) ? SC * 0.70710678118654752f : SC);
            }
        }
    }
}

extern "C" void kernel_launch(void* const* d_in, const int* in_sizes, int n_in,
                              void* d_out, int out_size, void* d_ws, size_t ws_size,
                              hipStream_t stream) {
    const float* x = (const float*)d_in[0];
    float* out = (float*)d_out;
    feat_mfma2<<<512, 256, 0, stream>>>(x, out);
}